// Round 8
// baseline (3714.725 us; speedup 1.0000x reference)
//
#include <hip/hip_runtime.h>
#include <math.h>

#define BB 16
#define CC 128
#define LL 16000
#define KK 256
#define SS 3937
#define MM 4000
#define THRS 0.5f
#define STEP 0.1f   // float32(0.01/0.1) == 0.1f

// ---------------------------------------------------------------------------
// Wt[k][c] = W[c][k]  (fp32, for coalesced LDS staging in k_conv)
// ---------------------------------------------------------------------------
__global__ void k_prepW(const float* __restrict__ W, float* __restrict__ Wt) {
    int idx = blockIdx.x * 256 + threadIdx.x;   // 0..32767
    int k = idx >> 7, c = idx & 127;
    Wt[k * CC + c] = W[c * KK + k];
}

// ---------------------------------------------------------------------------
// Strided conv1d (K=256, stride=4), fp32 register-tiled implicit GEMM.
// Accumulation: single fmaf chain per output, k strictly ascending 0..255.
// [bit-path: DO NOT change arithmetic order]
// MODE 0: in = x, epilogue drive = conv, u = 0.1f*conv (iter-1 analytic)
// MODE 1: in = recon (fp32), epilogue locked-fp32 LCA update of u
// ---------------------------------------------------------------------------
template<int MODE>
__global__ __launch_bounds__(256, 2) void k_conv(
    const float* __restrict__ in0,     // x (MODE 0) or recon (MODE 1), [B][LL]
    const float* __restrict__ Wt,      // [K][C]
    float* __restrict__ drive,
    float* __restrict__ u)
{
    __shared__ __align__(16) float sW[64 * 128];  // 32 KB W chunk
    __shared__ __align__(16) float sX[576];
    __shared__ int sFlag;

    const int tid = threadIdx.x;
    const int tx = tid & 15, ty = tid >> 4;
    const int s0 = blockIdx.x * 128;
    const int b  = blockIdx.y;

    float acc[8][8];
    #pragma unroll
    for (int i = 0; i < 8; ++i)
        #pragma unroll
        for (int j = 0; j < 8; ++j) acc[i][j] = 0.f;

    const int lbase0 = 4 * s0;

    for (int kc = 0; kc < 4; ++kc) {         // k chunks ascending
        const int k0 = kc * 64;
        if (MODE == 1 && tid == 0) sFlag = 0;
        __syncthreads();

        bool nz = false;
        for (int t = tid; t < 576; t += 256) {
            int l = lbase0 + k0 + t;
            float v = 0.f;
            if (l < LL) v = in0[b * LL + l];
            sX[t] = v;
            nz |= (v != 0.f);
        }
        if (MODE == 1) { if (nz) atomicOr(&sFlag, 1); }
        __syncthreads();

        const bool doit = (MODE == 0) || (sFlag != 0);   // block-uniform
        if (doit) {
            const float4* src = (const float4*)(Wt + k0 * CC);
            float4* dst = (float4*)sW;
            for (int t = tid; t < 2048; t += 256) dst[t] = src[t];
            __syncthreads();

            for (int kk4 = 0; kk4 < 16; ++kk4) {          // k ascending
                float xq[8][4];
                #pragma unroll
                for (int j = 0; j < 8; ++j) {
                    float4 t4 = *(const float4*)&sX[4 * (ty + 16 * j) + 4 * kk4];
                    xq[j][0] = t4.x; xq[j][1] = t4.y; xq[j][2] = t4.z; xq[j][3] = t4.w;
                }
                #pragma unroll
                for (int dk = 0; dk < 4; ++dk) {
                    float wv[8];
                    #pragma unroll
                    for (int i = 0; i < 8; ++i)
                        wv[i] = sW[(4 * kk4 + dk) * CC + tx + 16 * i];
                    #pragma unroll
                    for (int i = 0; i < 8; ++i)
                        #pragma unroll
                        for (int j = 0; j < 8; ++j)
                            acc[i][j] = fmaf(wv[i], xq[j][dk], acc[i][j]);
                }
            }
        }
    }

    // epilogue: locked fp32 elementwise chain (matches jnp expression tree)
    #pragma unroll
    for (int j = 0; j < 8; ++j) {
        int s = s0 + ty + 16 * j;
        if (s < SS) {
            #pragma unroll
            for (int i = 0; i < 8; ++i) {
                int c = tx + 16 * i;
                size_t idx = (size_t)(b * CC + c) * SS + s;
                if (MODE == 0) {
                    float d = acc[i][j];
                    drive[idx] = d;
                    u[idx] = __fmul_rn(STEP, d);   // u1 = 0 + 0.1f*drive
                } else {
                    float uo = u[idx];
                    float dr = drive[idx];
                    float a  = (fabsf(uo) > THRS) ? uo : 0.f;
                    float t1 = __fsub_rn(dr, uo);
                    float t2 = __fsub_rn(t1, acc[i][j]);
                    float t3 = __fadd_rn(t2, a);
                    float t4 = __fmul_rn(STEP, t3);
                    u[idx] = __fadd_rn(uo, t4);
                }
            }
        }
    }
}

// ---------------------------------------------------------------------------
// Transpose-conv (recon). Per-output fmaf chain IDENTICAL to rounds 5/6/7:
//   recon[b][4m+r]: for c = 0..127 asc, q = 0..63 asc (j = 63-q desc):
//       acc_r = fmaf(a[b][c][m-63+q], W[c][4*(63-q)+r], acc_r)
// Round-8 change: w4 fetched DIRECTLY from global W via the scalar path
// (wave-uniform address -> s_load_dwordx4, scalar cache) instead of LDS.
// LDS pipe now carries only the per-lane a b32 reads (halves pipe pressure,
// which round-7 counters showed is the bound). Arithmetic order unchanged.
// ---------------------------------------------------------------------------
__global__ __launch_bounds__(256, 2) void k_recon(
    const float* __restrict__ u,
    const float* __restrict__ W,       // [C][K] natural layout
    float* __restrict__ recon)         // [B][LL]
{
    __shared__ __align__(16) float sA[32 * 320];   // 40.96 KB (stride 320)
    __shared__ int sFlag;

    const int tid = threadIdx.x;      // = m_local in [0,256)
    const int m0 = blockIdx.x * 256;
    const int b  = blockIdx.y;
    const int m  = m0 + tid;

    if (tid == 0) sFlag = 0;
    __syncthreads();

    float acc0 = 0.f, acc1 = 0.f, acc2 = 0.f, acc3 = 0.f;

    for (int cs = 0; cs < 4; ++cs) {            // 32-channel stages, c ascending
        const int c0 = cs * 32;
        // stage a = hardshrink(u): rows cl in [0,32), cols [0,319) -> m' = m0-63+col
        bool nz = false;
        for (int cl = 0; cl < 32; ++cl) {
            const float* urow = u + (size_t)(b * CC + c0 + cl) * SS + (m0 - 63);
            #pragma unroll
            for (int h = 0; h < 2; ++h) {
                int col = tid + 256 * h;
                if (col < 319) {
                    int mm = m0 - 63 + col;
                    float v = 0.f;
                    if (mm >= 0 && mm < SS) {
                        float uu = urow[col];
                        v = (fabsf(uu) > THRS) ? uu : 0.f;
                    }
                    sA[cl * 320 + col] = v;
                    nz |= (v != 0.f);
                }
            }
        }
        if (nz) atomicOr(&sFlag, 1);
        __syncthreads();                        // staging + flags complete
        const int f = sFlag;                    // block-uniform read
        __syncthreads();                        // all threads have read f
        if (tid == 0) sFlag = 0;                // reset (ordered by loop-end barrier)

        if (f) {
            for (int cl = 0; cl < 32; ++cl) {   // c ascending
                const float* arow = sA + cl * 320 + tid;     // arow[q] = a[c][m-63+q]
                const float4* wrow = (const float4*)(W + (size_t)(c0 + cl) * KK);
                #pragma unroll 8
                for (int q = 0; q < 64; ++q) {  // j = 63-q descending
                    float v  = arow[q];          // LDS b32 (per-lane)
                    float4 w4 = wrow[63 - q];    // global, wave-uniform -> s_load
                    acc0 = fmaf(v, w4.x, acc0);
                    acc1 = fmaf(v, w4.y, acc1);
                    acc2 = fmaf(v, w4.z, acc2);
                    acc3 = fmaf(v, w4.w, acc3);
                }
            }
        }
        __syncthreads();   // sA reads done + sFlag reset visible before next stage
    }

    if (m < MM) {
        float4* o = (float4*)(recon + (size_t)b * LL + 4 * m);
        *o = make_float4(acc0, acc1, acc2, acc3);
    }
}

// ---------------------------------------------------------------------------
// Final: a = hardshrink(u) in place on d_out. 8062976 = 7874*256*4 exactly.
// ---------------------------------------------------------------------------
__global__ void k_out(float4* __restrict__ u4) {
    int idx = blockIdx.x * 256 + threadIdx.x;
    float4 v = u4[idx];
    v.x = (fabsf(v.x) > THRS) ? v.x : 0.f;
    v.y = (fabsf(v.y) > THRS) ? v.y : 0.f;
    v.z = (fabsf(v.z) > THRS) ? v.z : 0.f;
    v.w = (fabsf(v.w) > THRS) ? v.w : 0.f;
    u4[idx] = v;
}

extern "C" void kernel_launch(void* const* d_in, const int* in_sizes, int n_in,
                              void* d_out, int out_size, void* d_ws, size_t ws_size,
                              hipStream_t stream) {
    const float* x = (const float*)d_in[0];   // [16][1][16000]
    const float* W = (const float*)d_in[1];   // [128][1][256]
    float* u = (float*)d_out;                 // u lives in d_out (fp32)

    float* ws    = (float*)d_ws;              // ~33.4 MB used
    float* drive = ws;                                   // 8062976
    float* recon = drive + (size_t)BB * CC * SS;         // 256000
    float* Wt    = recon + (size_t)BB * LL;              // 32768

    k_prepW<<<128, 256, 0, stream>>>(W, Wt);

    dim3 gConv(31, 16);   // ceil(3937/128) x B
    k_conv<0><<<gConv, 256, 0, stream>>>(x, Wt, drive, u);   // drive + u1

    for (int it = 0; it < 9; ++it) {   // iterations 2..10
        k_recon<<<dim3(16, 16), 256, 0, stream>>>(u, W, recon);
        k_conv<1><<<gConv, 256, 0, stream>>>(recon, Wt, drive, u);
    }

    k_out<<<7874, 256, 0, stream>>>((float4*)u);
}

// Round 9
// 2479.416 us; speedup vs baseline: 1.4982x; 1.4982x over previous
//
#include <hip/hip_runtime.h>
#include <math.h>

#define BB 16
#define CC 128
#define LL 16000
#define KK 256
#define SS 3937
#define MM 4000
#define THRS 0.5f
#define STEP 0.1f   // float32(0.01/0.1) == 0.1f

// ---------------------------------------------------------------------------
// Wt[k][c] = W[c][k]  (fp32, for coalesced LDS staging in k_conv)
// ---------------------------------------------------------------------------
__global__ void k_prepW(const float* __restrict__ W, float* __restrict__ Wt) {
    int idx = blockIdx.x * 256 + threadIdx.x;   // 0..32767
    int k = idx >> 7, c = idx & 127;
    Wt[k * CC + c] = W[c * KK + k];
}

// ---------------------------------------------------------------------------
// Strided conv1d (K=256, stride=4), fp32 register-tiled implicit GEMM.
// Accumulation: single fmaf chain per output, k strictly ascending 0..255.
// [bit-path: DO NOT change arithmetic order]
// MODE 0: in = x, epilogue drive = conv, u = 0.1f*conv (iter-1 analytic)
// MODE 1: in = recon (fp32), epilogue locked-fp32 LCA update of u
// ---------------------------------------------------------------------------
template<int MODE>
__global__ __launch_bounds__(256, 2) void k_conv(
    const float* __restrict__ in0,     // x (MODE 0) or recon (MODE 1), [B][LL]
    const float* __restrict__ Wt,      // [K][C]
    float* __restrict__ drive,
    float* __restrict__ u)
{
    __shared__ __align__(16) float sW[64 * 128];  // 32 KB W chunk
    __shared__ __align__(16) float sX[576];
    __shared__ int sFlag;

    const int tid = threadIdx.x;
    const int tx = tid & 15, ty = tid >> 4;
    const int s0 = blockIdx.x * 128;
    const int b  = blockIdx.y;

    float acc[8][8];
    #pragma unroll
    for (int i = 0; i < 8; ++i)
        #pragma unroll
        for (int j = 0; j < 8; ++j) acc[i][j] = 0.f;

    const int lbase0 = 4 * s0;

    for (int kc = 0; kc < 4; ++kc) {         // k chunks ascending
        const int k0 = kc * 64;
        if (MODE == 1 && tid == 0) sFlag = 0;
        __syncthreads();

        bool nz = false;
        for (int t = tid; t < 576; t += 256) {
            int l = lbase0 + k0 + t;
            float v = 0.f;
            if (l < LL) v = in0[b * LL + l];
            sX[t] = v;
            nz |= (v != 0.f);
        }
        if (MODE == 1) { if (nz) atomicOr(&sFlag, 1); }
        __syncthreads();

        const bool doit = (MODE == 0) || (sFlag != 0);   // block-uniform
        if (doit) {
            const float4* src = (const float4*)(Wt + k0 * CC);
            float4* dst = (float4*)sW;
            for (int t = tid; t < 2048; t += 256) dst[t] = src[t];
            __syncthreads();

            for (int kk4 = 0; kk4 < 16; ++kk4) {          // k ascending
                float xq[8][4];
                #pragma unroll
                for (int j = 0; j < 8; ++j) {
                    float4 t4 = *(const float4*)&sX[4 * (ty + 16 * j) + 4 * kk4];
                    xq[j][0] = t4.x; xq[j][1] = t4.y; xq[j][2] = t4.z; xq[j][3] = t4.w;
                }
                #pragma unroll
                for (int dk = 0; dk < 4; ++dk) {
                    float wv[8];
                    #pragma unroll
                    for (int i = 0; i < 8; ++i)
                        wv[i] = sW[(4 * kk4 + dk) * CC + tx + 16 * i];
                    #pragma unroll
                    for (int i = 0; i < 8; ++i)
                        #pragma unroll
                        for (int j = 0; j < 8; ++j)
                            acc[i][j] = fmaf(wv[i], xq[j][dk], acc[i][j]);
                }
            }
        }
    }

    // epilogue: locked fp32 elementwise chain (matches jnp expression tree)
    #pragma unroll
    for (int j = 0; j < 8; ++j) {
        int s = s0 + ty + 16 * j;
        if (s < SS) {
            #pragma unroll
            for (int i = 0; i < 8; ++i) {
                int c = tx + 16 * i;
                size_t idx = (size_t)(b * CC + c) * SS + s;
                if (MODE == 0) {
                    float d = acc[i][j];
                    drive[idx] = d;
                    u[idx] = __fmul_rn(STEP, d);   // u1 = 0 + 0.1f*drive
                } else {
                    float uo = u[idx];
                    float dr = drive[idx];
                    float a  = (fabsf(uo) > THRS) ? uo : 0.f;
                    float t1 = __fsub_rn(dr, uo);
                    float t2 = __fsub_rn(t1, acc[i][j]);
                    float t3 = __fadd_rn(t2, a);
                    float t4 = __fmul_rn(STEP, t3);
                    u[idx] = __fadd_rn(uo, t4);
                }
            }
        }
    }
}

// ---------------------------------------------------------------------------
// float readlane via int builtin (lane must be compile-time constant here)
// ---------------------------------------------------------------------------
__device__ __forceinline__ float rdlane_f(float v, int lane) {
    union { float f; int i; } u;
    u.f = v;
    u.i = __builtin_amdgcn_readlane(u.i, lane);
    return u.f;
}

// ---------------------------------------------------------------------------
// Transpose-conv (recon). Per-output fmaf chain IDENTICAL to rounds 5-8:
//   recon[b][4m+r]: for c = 0..127 asc, q = 0..63 asc (j = 63-q desc):
//       acc_r = fmaf(a[b][c][m-63+q], W[c][4*(63-q)+r], acc_r)
// Round-9 w-path: per cl, lane l loads wv = W[c][4l..4l+3] (ONE coalesced,
// L1-hot global b128 per wave). In the fully-unrolled q loop, w components
// come from v_readlane(wv, 63-q) — VALU, zero LDS. LDS pipe carries only the
// per-lane a b32 reads (R7 counters showed the w b128 was 2/3 of the pipe).
// R8 lesson: compiler will NOT scalarize uniform inner-loop global loads.
// ---------------------------------------------------------------------------
__global__ __launch_bounds__(256, 2) void k_recon(
    const float* __restrict__ u,
    const float* __restrict__ W,       // [C][K] natural layout
    float* __restrict__ recon)         // [B][LL]
{
    __shared__ __align__(16) float sA[32 * 320];   // 40.96 KB (stride 320)
    __shared__ int sFlag;

    const int tid = threadIdx.x;      // = m_local in [0,256)
    const int lane = tid & 63;
    const int m0 = blockIdx.x * 256;
    const int b  = blockIdx.y;
    const int m  = m0 + tid;

    if (tid == 0) sFlag = 0;
    __syncthreads();

    float acc0 = 0.f, acc1 = 0.f, acc2 = 0.f, acc3 = 0.f;

    for (int cs = 0; cs < 4; ++cs) {            // 32-channel stages, c ascending
        const int c0 = cs * 32;
        // stage a = hardshrink(u): rows cl in [0,32), cols [0,319) -> m' = m0-63+col
        bool nz = false;
        for (int cl = 0; cl < 32; ++cl) {
            const float* urow = u + (size_t)(b * CC + c0 + cl) * SS + (m0 - 63);
            #pragma unroll
            for (int h = 0; h < 2; ++h) {
                int col = tid + 256 * h;
                if (col < 319) {
                    int mm = m0 - 63 + col;
                    float v = 0.f;
                    if (mm >= 0 && mm < SS) {
                        float uu = urow[col];
                        v = (fabsf(uu) > THRS) ? uu : 0.f;
                    }
                    sA[cl * 320 + col] = v;
                    nz |= (v != 0.f);
                }
            }
        }
        if (nz) atomicOr(&sFlag, 1);
        __syncthreads();                        // staging + flags complete
        const int f = sFlag;                    // block-uniform read
        __syncthreads();                        // all threads have read f
        if (tid == 0) sFlag = 0;                // reset (ordered by loop-end barrier)

        if (f) {
            for (int cl = 0; cl < 32; ++cl) {   // c ascending
                const float* arow = sA + cl * 320 + tid;     // arow[q] = a[c][m-63+q]
                // lane l holds W[c][4l .. 4l+3]; one coalesced b128 per wave
                float4 wv = ((const float4*)(W + (size_t)(c0 + cl) * KK))[lane];
                #pragma unroll
                for (int q = 0; q < 64; ++q) {  // j = 63-q descending
                    float v  = arow[q];          // LDS b32 (pairable -> ds_read2)
                    float wx = rdlane_f(wv.x, 63 - q);
                    float wy = rdlane_f(wv.y, 63 - q);
                    float wz = rdlane_f(wv.z, 63 - q);
                    float ww = rdlane_f(wv.w, 63 - q);
                    acc0 = fmaf(v, wx, acc0);
                    acc1 = fmaf(v, wy, acc1);
                    acc2 = fmaf(v, wz, acc2);
                    acc3 = fmaf(v, ww, acc3);
                }
            }
        }
        __syncthreads();   // sA reads done + sFlag reset visible before next stage
    }

    if (m < MM) {
        float4* o = (float4*)(recon + (size_t)b * LL + 4 * m);
        *o = make_float4(acc0, acc1, acc2, acc3);
    }
}

// ---------------------------------------------------------------------------
// Final: a = hardshrink(u) in place on d_out. 8062976 = 7874*256*4 exactly.
// ---------------------------------------------------------------------------
__global__ void k_out(float4* __restrict__ u4) {
    int idx = blockIdx.x * 256 + threadIdx.x;
    float4 v = u4[idx];
    v.x = (fabsf(v.x) > THRS) ? v.x : 0.f;
    v.y = (fabsf(v.y) > THRS) ? v.y : 0.f;
    v.z = (fabsf(v.z) > THRS) ? v.z : 0.f;
    v.w = (fabsf(v.w) > THRS) ? v.w : 0.f;
    u4[idx] = v;
}

extern "C" void kernel_launch(void* const* d_in, const int* in_sizes, int n_in,
                              void* d_out, int out_size, void* d_ws, size_t ws_size,
                              hipStream_t stream) {
    const float* x = (const float*)d_in[0];   // [16][1][16000]
    const float* W = (const float*)d_in[1];   // [128][1][256]
    float* u = (float*)d_out;                 // u lives in d_out (fp32)

    float* ws    = (float*)d_ws;              // ~33.4 MB used
    float* drive = ws;                                   // 8062976
    float* recon = drive + (size_t)BB * CC * SS;         // 256000
    float* Wt    = recon + (size_t)BB * LL;              // 32768

    k_prepW<<<128, 256, 0, stream>>>(W, Wt);

    dim3 gConv(31, 16);   // ceil(3937/128) x B
    k_conv<0><<<gConv, 256, 0, stream>>>(x, Wt, drive, u);   // drive + u1

    for (int it = 0; it < 9; ++it) {   // iterations 2..10
        k_recon<<<dim3(16, 16), 256, 0, stream>>>(u, W, recon);
        k_conv<1><<<gConv, 256, 0, stream>>>(recon, Wt, drive, u);
    }

    k_out<<<7874, 256, 0, stream>>>((float4*)u);
}